// Round 11
// baseline (2418.831 us; speedup 1.0000x reference)
//
#include <hip/hip_runtime.h>
#include <stdint.h>
#include <stddef.h>

typedef __attribute__((ext_vector_type(8))) short short8;
typedef __attribute__((ext_vector_type(4))) float f32x4;
typedef unsigned int u32;
typedef unsigned long long u64;

__device__ inline unsigned short f2bf(float f) {
  union { float f; uint32_t u; } v; v.f = f;
  uint32_t u = v.u;
  u += 0x7FFFu + ((u >> 16) & 1u);
  return (unsigned short)(u >> 16);
}
__device__ inline float bf2f(unsigned short h) {
  union { uint32_t u; float f; } v; v.u = ((uint32_t)h) << 16; return v.f;
}
__device__ inline short8 pack8(float4 a, float4 b) {
  short8 r;
  r[0] = (short)f2bf(a.x); r[1] = (short)f2bf(a.y);
  r[2] = (short)f2bf(a.z); r[3] = (short)f2bf(a.w);
  r[4] = (short)f2bf(b.x); r[5] = (short)f2bf(b.y);
  r[6] = (short)f2bf(b.z); r[7] = (short)f2bf(b.w);
  return r;
}
__device__ inline float tanh_fast(float x) {
  float xc = fminf(fmaxf(x, -9.f), 9.f);
  float e = __expf(2.f * xc);
  return (e - 1.f) * __builtin_amdgcn_rcpf(e + 1.f);
}
__device__ inline float sigm_fast(float x) {
  float xc = fminf(fmaxf(x, -30.f), 30.f);
  return __builtin_amdgcn_rcpf(1.f + __expf(-xc));
}
__device__ inline u64 pack2f(float a, float b) {
  return (u64)__float_as_uint(a) | ((u64)__float_as_uint(b) << 32);
}
// LLC mailbox primitives (r5/r6-verified fast flag propagation; r5/r6 data
// corruption was a layout bug, fixed here). Writes: returning exchange
// (commits at the device coherence point before vmcnt retires). Reads:
// relaxed fetch_add(0) RMW (executes at LLC, no cache invalidates).
__device__ inline void st_x64(u64* p, u64 v) {
  u64 old = __hip_atomic_exchange(p, v, __ATOMIC_RELAXED, __HIP_MEMORY_SCOPE_AGENT);
  asm volatile("" :: "v"(old));
}
__device__ inline u64 ld_x64(u64* p) {
  return __hip_atomic_fetch_add(p, 0ULL, __ATOMIC_RELAXED, __HIP_MEMORY_SCOPE_AGENT);
}
__device__ inline void st_flag(int* f) {
  int old = __hip_atomic_exchange(f, 1, __ATOMIC_RELAXED, __HIP_MEMORY_SCOPE_AGENT);
  asm volatile("" :: "v"(old));
}
__device__ inline int ld_flag(int* f) {
  return __hip_atomic_fetch_add(f, 0, __ATOMIC_RELAXED, __HIP_MEMORY_SCOPE_AGENT);
}
// Wave 0 polls n flags; spin-capped (broken case terminates, never hangs).
__device__ inline void poll_flags(int* base, int n, int tid) {
  if (tid < 64) {
    bool done = tid >= n;
    for (int it = 0; it < (1 << 17); ++it) {
      if (!done) done = ld_flag(base + tid) != 0;
      if (__all((int)done)) break;
      __builtin_amdgcn_s_sleep(2);
    }
  }
  __syncthreads();
}
// async global->LDS, 16 bytes per lane (wave-uniform LDS base + lane*16)
__device__ inline void gl_lds16(const unsigned short* g, unsigned short* l) {
  __builtin_amdgcn_global_load_lds(
      (const __attribute__((address_space(1))) u32*)g,
      (__attribute__((address_space(3))) u32*)l, 16, 0, 0);
}

// Gather + bf16-convert embeddings.
__global__ __launch_bounds__(128) void prep_gather(
    const int* __restrict__ src, const int* __restrict__ trg,
    const float* __restrict__ emb,
    unsigned short* __restrict__ xbf, unsigned short* __restrict__ ebf,
    unsigned short* __restrict__ Zbf) {
  int r = blockIdx.x, tid = threadIdx.x;
  if (r < 2048) {
    int b = r & 31, s = r >> 5;
    int tok = src[b * 64 + s];
    const float* e = emb + (size_t)tok * 512;
    float4 v = *(const float4*)(e + tid * 4);
    unsigned short* dst = xbf + (size_t)r * 512 + tid * 4;
    dst[0] = f2bf(v.x); dst[1] = f2bf(v.y); dst[2] = f2bf(v.z); dst[3] = f2bf(v.w);
  } else {
    int rr = r - 2048;
    int t = rr >> 5, b = rr & 31;
    unsigned short* dst = ebf + (size_t)rr * 512 + tid * 4;
    if (t < 47) {
      int tok = trg[t * 32 + b];
      const float* e = emb + (size_t)tok * 512;
      float4 v = *(const float4*)(e + tid * 4);
      unsigned short q0 = f2bf(v.x), q1 = f2bf(v.y), q2 = f2bf(v.z), q3 = f2bf(v.w);
      dst[0] = q0; dst[1] = q1; dst[2] = q2; dst[3] = q3;
      unsigned short* zd = Zbf + (size_t)rr * 2048 + 1536 + tid * 4;
      zd[0] = q0; zd[1] = q1; zd[2] = q2; zd[3] = q3;
    } else {
      dst[0] = 0; dst[1] = 0; dst[2] = 0; dst[3] = 0;
    }
  }
}

// All recurrent-weight f32->bf16 conversions in one launch.
__global__ __launch_bounds__(64) void cvt_weights(
    const float* __restrict__ encfW, const float* __restrict__ encbW,
    const float* __restrict__ attnW, const float* __restrict__ decWhh,
    unsigned short* __restrict__ whFbf, unsigned short* __restrict__ whBbf,
    unsigned short* __restrict__ Wcat) {
  int r = blockIdx.x, c = threadIdx.x * 8;
  const float* s;
  unsigned short* d;
  if (r < 1536) { s = encfW + (size_t)r * 512 + c; d = whFbf + (size_t)r * 512 + c; }
  else if (r < 3072) { int q = r - 1536; s = encbW + (size_t)q * 512 + c; d = whBbf + (size_t)q * 512 + c; }
  else if (r < 3584) { int q = r - 3072; s = attnW + (size_t)q * 1536 + c; d = Wcat + (size_t)q * 512 + c; }
  else { int q = r - 3584; s = decWhh + (size_t)q * 512 + c; d = Wcat + (size_t)(q + 512) * 512 + c; }
  *(short8*)d = pack8(*(const float4*)s, *(const float4*)(s + 4));
}

// C[m,n] = sum_k A[m,k]*B[n,k] (+bias[n]). 128x128 tile, BK=32, 4 waves.
template <bool ABF, bool BBF, bool WBF>
__global__ __launch_bounds__(256) void gemm_kernel(
    const void* __restrict__ Av, int lda,
    const void* __restrict__ Bv, int ldb, int bco,
    const float* __restrict__ bias,
    void* __restrict__ Cv, int ldc,
    int K, int Mvalid, int row_off) {
  __shared__ __align__(16) unsigned short As[128 * 32];
  __shared__ __align__(16) unsigned short Bs[128 * 32];
  const int tid = threadIdx.x;
  const int m0 = blockIdx.x * 128, n0 = blockIdx.y * 128;
  const int w = tid >> 6, lane = tid & 63;
  const int wm = w >> 1, wn = w & 1;
  const int fr = lane & 15, fq = lane >> 4;
  f32x4 acc[4][4];
#pragma unroll
  for (int mi = 0; mi < 4; ++mi)
#pragma unroll
    for (int ni = 0; ni < 4; ++ni) acc[mi][ni] = (f32x4){0.f, 0.f, 0.f, 0.f};
  for (int k0 = 0; k0 < K; k0 += 32) {
#pragma unroll
    for (int p = 0; p < 2; ++p) {
      int idx = p * 256 + tid;
      int row = idx >> 2, seg = idx & 3;
      if (ABF) {
        const unsigned short* Ab = (const unsigned short*)Av;
        *(short8*)(As + row * 32 + seg * 8) =
            *(const short8*)(Ab + (size_t)(m0 + row) * lda + k0 + seg * 8);
      } else {
        const float* Af = (const float*)Av;
        const float* ap = Af + (size_t)(m0 + row) * lda + k0 + seg * 8;
        *(short8*)(As + row * 32 + seg * 8) = pack8(*(const float4*)ap, *(const float4*)(ap + 4));
      }
      if (BBF) {
        const unsigned short* Bb = (const unsigned short*)Bv;
        *(short8*)(Bs + row * 32 + seg * 8) =
            *(const short8*)(Bb + (size_t)(n0 + row) * ldb + bco + k0 + seg * 8);
      } else {
        const float* Bf = (const float*)Bv;
        const float* bp = Bf + (size_t)(n0 + row) * ldb + bco + k0 + seg * 8;
        *(short8*)(Bs + row * 32 + seg * 8) = pack8(*(const float4*)bp, *(const float4*)(bp + 4));
      }
    }
    __syncthreads();
    short8 af[4], bfr[4];
#pragma unroll
    for (int mi = 0; mi < 4; ++mi)
      af[mi] = *(const short8*)(As + (wm * 64 + mi * 16 + fr) * 32 + fq * 8);
#pragma unroll
    for (int ni = 0; ni < 4; ++ni)
      bfr[ni] = *(const short8*)(Bs + (wn * 64 + ni * 16 + fr) * 32 + fq * 8);
#pragma unroll
    for (int mi = 0; mi < 4; ++mi)
#pragma unroll
      for (int ni = 0; ni < 4; ++ni)
        acc[mi][ni] = __builtin_amdgcn_mfma_f32_16x16x32_bf16(af[mi], bfr[ni], acc[mi][ni], 0, 0, 0);
    __syncthreads();
  }
#pragma unroll
  for (int mi = 0; mi < 4; ++mi)
#pragma unroll
    for (int ni = 0; ni < 4; ++ni) {
      int col = n0 + wn * 64 + ni * 16 + fr;
      float bv = bias ? bias[col] : 0.f;
#pragma unroll
      for (int j = 0; j < 4; ++j) {
        int rowm = m0 + wm * 64 + mi * 16 + fq * 4 + j;
        if (rowm < Mvalid) {
          float val = acc[mi][ni][j] + bv;
          if (WBF)
            ((unsigned short*)Cv)[(size_t)(rowm + row_off) * ldc + col] = f2bf(val);
          else
            ((float*)Cv)[(size_t)(rowm + row_off) * ldc + col] = val;
        }
      }
    }
}

// Output projection, 8-phase 256x256 schedule (unchanged from r10: swizzle
// byte ^= ((row&7)<<4), conflict-free; XCD-swizzled grid).
__global__ __launch_bounds__(512, 1) void gemm_big8(
    const unsigned short* __restrict__ A,
    const unsigned short* __restrict__ B,
    const float* __restrict__ bias,
    float* __restrict__ C) {
  extern __shared__ char lds[];
  char* LA = lds;
  char* LB = lds + 65536;
  const int tid = threadIdx.x;
  const int w = tid >> 6, lane = tid & 63;
  int wg = blockIdx.x;
  {
    int x = wg & 7, i = wg >> 3;
    wg = (x < 6 ? x * 94 : 564 + (x - 6) * 93) + i;
  }
  const int m0 = (wg % 6) * 256, n0 = (wg / 6) * 256;
  const int wm = w >> 2, wn = w & 3;
  const int fr = lane & 15, fq = lane >> 4;

  auto stage = [&](const unsigned short* G, char* L, int rowbase, int kt, int h, int c) {
#pragma unroll
    for (int j = 0; j < 2; ++j) {
      int pbh = j * 8192 + w * 1024;
      int pl = pbh + lane * 16;
      int lb = pl ^ (((pl >> 7) & 7) << 4);
      int rl = lb >> 7, ch = (lb >> 4) & 7;
      gl_lds16(G + (size_t)(rowbase + h * 128 + rl) * 2048 + kt * 64 + ch * 8,
               (unsigned short*)(L + c * 32768 + h * 16384 + pbh));
    }
  };

  f32x4 acc[8][4];
#pragma unroll
  for (int mi = 0; mi < 8; ++mi)
#pragma unroll
    for (int ni = 0; ni < 4; ++ni) acc[mi][ni] = (f32x4){0.f, 0.f, 0.f, 0.f};

  stage(A, LA, m0, 0, 0, 0); stage(B, LB, n0, 0, 0, 0);
  stage(A, LA, m0, 0, 1, 0); stage(B, LB, n0, 0, 1, 0);
  asm volatile("s_waitcnt vmcnt(0)" ::: "memory");
  __builtin_amdgcn_s_barrier();

  short8 bfrag[8];
  for (int kt = 0; kt < 32; ++kt) {
    const int c = kt & 1;
    char* Abuf = LA + c * 32768;
    char* Bbuf = LB + c * 32768;
#pragma unroll
    for (int p = 0; p < 4; ++p) {
      if (kt < 31) {
        if (p == 0) {
          stage(A, LA, m0, kt + 1, 0, c ^ 1);
          stage(B, LB, n0, kt + 1, 0, c ^ 1);
        } else if (p == 1) {
          stage(A, LA, m0, kt + 1, 1, c ^ 1);
          stage(B, LB, n0, kt + 1, 1, c ^ 1);
        }
      }
      if (p == 0) {
#pragma unroll
        for (int ni = 0; ni < 4; ++ni)
#pragma unroll
          for (int ks = 0; ks < 2; ++ks) {
            int n = wn * 64 + ni * 16 + fr;
            int h = n >> 7, nl = n & 127;
            int lb = nl * 128 + ks * 64 + fq * 16;
            int pb = lb ^ (((lb >> 7) & 7) << 4);
            bfrag[ni * 2 + ks] = *(const short8*)(Bbuf + h * 16384 + pb);
          }
      }
      short8 afrag[4];
#pragma unroll
      for (int q = 0; q < 2; ++q)
#pragma unroll
        for (int ks = 0; ks < 2; ++ks) {
          int r = wm * 128 + (2 * p + q) * 16 + fr;
          int h = r >> 7, rl = r & 127;
          int lb = rl * 128 + ks * 64 + fq * 16;
          int pb = lb ^ (((lb >> 7) & 7) << 4);
          afrag[q * 2 + ks] = *(const short8*)(Abuf + h * 16384 + pb);
        }
      __builtin_amdgcn_s_setprio(1);
#pragma unroll
      for (int q = 0; q < 2; ++q)
#pragma unroll
        for (int ni = 0; ni < 4; ++ni)
#pragma unroll
          for (int ks = 0; ks < 2; ++ks)
            acc[2 * p + q][ni] = __builtin_amdgcn_mfma_f32_16x16x32_bf16(
                afrag[q * 2 + ks], bfrag[ni * 2 + ks], acc[2 * p + q][ni], 0, 0, 0);
      __builtin_amdgcn_s_setprio(0);
      if (p == 3) asm volatile("s_waitcnt vmcnt(0)" ::: "memory");
      __builtin_amdgcn_s_barrier();
    }
  }
#pragma unroll
  for (int mi = 0; mi < 8; ++mi)
#pragma unroll
    for (int ni = 0; ni < 4; ++ni) {
      int col = n0 + wn * 64 + ni * 16 + fr;
      float bv = bias[col];
#pragma unroll
      for (int j = 0; j < 4; ++j) {
        int row = m0 + wm * 128 + mi * 16 + fq * 4 + j;
        if (row < 1504) C[(size_t)(row + 32) * 32000 + col] = acc[mi][ni][j] + bv;
      }
    }
}

// Persistent bidirectional encoder: 32 GRU blocks (dir x 32-d slice), all 64
// steps in one launch via LLC mailboxes; blocks 32+ stream-convert out_W.
__global__ __launch_bounds__(512, 1) void enc_all(
    const float* __restrict__ Gif, const float* __restrict__ Gib,
    const unsigned short* __restrict__ whFbf, const unsigned short* __restrict__ whBbf,
    const float* __restrict__ bhhF, const float* __restrict__ bhhB,
    u64* hmb,                           // [dir][2][4096] u64 (32x512 bf16/buf)
    unsigned short* __restrict__ ebo,   // [b][s][1024] bf16
    float* __restrict__ hcat,           // [b][1024] f32
    const float* __restrict__ outW, unsigned short* __restrict__ outWbf,
    long long nCvt4, int* hflag) {
  const int blk = blockIdx.x, tid = threadIdx.x;
  if (blk >= 32) {
    long long i = (long long)(blk - 32) * 512 + tid;
    long long stride = (long long)(gridDim.x - 32) * 512;
    for (; i < nCvt4; i += stride) {
      float4 v = ((const float4*)outW)[i];
      unsigned short* d = outWbf + i * 4;
      d[0] = f2bf(v.x); d[1] = f2bf(v.y); d[2] = f2bf(v.z); d[3] = f2bf(v.w);
    }
    return;
  }
  const int dir = blk >> 4, slice = blk & 15, D0 = slice * 32;
  const unsigned short* Wbf = dir ? whBbf : whFbf;
  const float* Gi = dir ? Gib : Gif;
  const float* bhh = dir ? bhhB : bhhF;
  __shared__ __align__(16) unsigned short hlds[32 * 520];
  __shared__ __align__(16) float gl[96 * 33];
  __shared__ __align__(16) unsigned short pub[32 * 32];
  u64* hb = hmb + (size_t)dir * 8192;
  int* mf = hflag + dir * 1024;
  const int w = tid >> 6, lane = tid & 63, fr = lane & 15, fq = lane >> 4;
  float hprev[2] = {0.f, 0.f};
  for (int t = 0; t < 64; ++t) {
    // read h mailbox (zeros at t=0 via memset)
    {
      u64* hs = hb + (t & 1) * 4096;
      u64 t0 = ld_x64(hs + tid), t1 = ld_x64(hs + tid + 512);
      u64 t2 = ld_x64(hs + tid + 1024), t3 = ld_x64(hs + tid + 1536);
      u64 t4 = ld_x64(hs + tid + 2048), t5 = ld_x64(hs + tid + 2560);
      u64 t6 = ld_x64(hs + tid + 3072), t7 = ld_x64(hs + tid + 3584);
      int i0 = tid;
      *(u64*)(hlds + ((i0) >> 7) * 520 + ((i0) & 127) * 4) = t0;
      *(u64*)(hlds + ((i0 + 512) >> 7) * 520 + ((i0 + 512) & 127) * 4) = t1;
      *(u64*)(hlds + ((i0 + 1024) >> 7) * 520 + ((i0 + 1024) & 127) * 4) = t2;
      *(u64*)(hlds + ((i0 + 1536) >> 7) * 520 + ((i0 + 1536) & 127) * 4) = t3;
      *(u64*)(hlds + ((i0 + 2048) >> 7) * 520 + ((i0 + 2048) & 127) * 4) = t4;
      *(u64*)(hlds + ((i0 + 2560) >> 7) * 520 + ((i0 + 2560) & 127) * 4) = t5;
      *(u64*)(hlds + ((i0 + 3072) >> 7) * 520 + ((i0 + 3072) & 127) * 4) = t6;
      *(u64*)(hlds + ((i0 + 3584) >> 7) * 520 + ((i0 + 3584) & 127) * 4) = t7;
    }
    __syncthreads();
    if (w < 6) {
      int row = w * 16 + fr;
      int gr = (row >> 5) * 512 + D0 + (row & 31);
      const unsigned short* wrow = Wbf + (size_t)gr * 512;
      f32x4 acc0 = {0.f, 0.f, 0.f, 0.f}, acc1 = {0.f, 0.f, 0.f, 0.f};
#pragma unroll
      for (int k0 = 0; k0 < 512; k0 += 32) {
        short8 bq = *(const short8*)(wrow + k0 + fq * 8);
        short8 a0 = *(const short8*)(hlds + fr * 520 + k0 + fq * 8);
        short8 a1 = *(const short8*)(hlds + (16 + fr) * 520 + k0 + fq * 8);
        acc0 = __builtin_amdgcn_mfma_f32_16x16x32_bf16(a0, bq, acc0, 0, 0, 0);
        acc1 = __builtin_amdgcn_mfma_f32_16x16x32_bf16(a1, bq, acc1, 0, 0, 0);
      }
#pragma unroll
      for (int j = 0; j < 4; ++j) {
        gl[row * 33 + fq * 4 + j] = acc0[j];
        gl[row * 33 + 16 + fq * 4 + j] = acc1[j];
      }
    }
    __syncthreads();
    const int srow = dir ? 63 - t : t;
#pragma unroll
    for (int rep = 0; rep < 2; ++rep) {
      int idx = rep * 512 + tid, b = idx >> 5, dl = idx & 31, d = D0 + dl;
      float ar = gl[dl * 33 + b] + bhh[d];
      float az = gl[(32 + dl) * 33 + b] + bhh[512 + d];
      float an = gl[(64 + dl) * 33 + b] + bhh[1024 + d];
      const float* gi = Gi + ((size_t)srow * 32 + b) * 1536;
      float r = sigm_fast(gi[d] + ar);
      float z = sigm_fast(gi[512 + d] + az);
      float n = tanh_fast(gi[1024 + d] + r * an);
      float h2 = (1.f - z) * n + z * hprev[rep];
      hprev[rep] = h2;
      pub[b * 32 + dl] = f2bf(h2);
      ebo[((size_t)b * 64 + srow) * 1024 + (size_t)dir * 512 + d] = f2bf(h2);
      if (t == 63) hcat[(size_t)b * 1024 + (size_t)dir * 512 + d] = h2;
    }
    __syncthreads();
    if (t < 63) {
      if (tid < 256) {
        int b = tid >> 3, c4 = tid & 7;
        st_x64(hb + ((t + 1) & 1) * 4096 + b * 128 + (D0 >> 2) + c4,
               *(const u64*)(pub + b * 32 + c4 * 4));
      }
      asm volatile("s_waitcnt vmcnt(0)" ::: "memory");
      __syncthreads();
      if (tid == 0) st_flag(&mf[t * 16 + slice]);
      poll_flags(&mf[t * 16], 16, tid);
    }
  }
}

__global__ __launch_bounds__(512) void tanh_s0(const float* __restrict__ s0raw,
                                               float* __restrict__ sf32,
                                               unsigned short* __restrict__ sbf) {
  int idx = blockIdx.x * 512 + threadIdx.x;
  float v = tanhf(s0raw[idx]);
  sf32[idx] = v;
  sbf[idx] = f2bf(v);
}

// Persistent decoder: blocks 0..31 = G (sproj+gh MFMA), 32..63 = B (one per
// batch: scores/softmax/context/gic/gates). All 47 steps in one launch via
// LLC mailboxes. s-mailbox: 4096 u64 per parity buffer, 128 u64/row (FIXED).
__global__ __launch_bounds__(512, 1) void dec_all(
    const unsigned short* __restrict__ Wcat, const float* __restrict__ decBhh,
    const float* __restrict__ attnV,
    u64* smb, const float* __restrict__ s0f,
    const unsigned short* __restrict__ epf, const unsigned short* __restrict__ ebo,
    const unsigned short* __restrict__ EP2b, const float* __restrict__ Gie,
    u64* gout64, unsigned short* __restrict__ Zbf,
    int* gflag, int* sflag) {
  __shared__ __align__(16) char smem[43008];
  const int blk = blockIdx.x, tid = threadIdx.x;
  if (blk < 32) {
    // ---- G role: cols n in [g*64, g*64+64) of gout[b][2048] ----
    const int g = blk;
    unsigned short* slds = (unsigned short*)smem;            // 32*520 bf16
    float* glds = (float*)(smem + 33280);                    // 32*68 f32
    const int w = tid >> 6, lane = tid & 63, fr = lane & 15, fq = lane >> 4;
    const int mt = w >> 2, nt = w & 3;
    const int rc = g * 64 + nt * 16 + fr;
    const unsigned short* wrow = Wcat + (size_t)rc * 512;
    const float bv = rc < 512 ? 0.f : decBhh[rc - 512];
    for (int t = 0; t < 47; ++t) {
      if (t > 0) poll_flags(&sflag[(t - 1) * 32], 32, tid);
      {
        u64* ss = smb + (t & 1) * 4096;
        u64 t0 = ld_x64(ss + tid), t1 = ld_x64(ss + tid + 512);
        u64 t2 = ld_x64(ss + tid + 1024), t3 = ld_x64(ss + tid + 1536);
        u64 t4 = ld_x64(ss + tid + 2048), t5 = ld_x64(ss + tid + 2560);
        u64 t6 = ld_x64(ss + tid + 3072), t7 = ld_x64(ss + tid + 3584);
        int i0 = tid;
        *(u64*)(slds + ((i0) >> 7) * 520 + ((i0) & 127) * 4) = t0;
        *(u64*)(slds + ((i0 + 512) >> 7) * 520 + ((i0 + 512) & 127) * 4) = t1;
        *(u64*)(slds + ((i0 + 1024) >> 7) * 520 + ((i0 + 1024) & 127) * 4) = t2;
        *(u64*)(slds + ((i0 + 1536) >> 7) * 520 + ((i0 + 1536) & 127) * 4) = t3;
        *(u64*)(slds + ((i0 + 2048) >> 7) * 520 + ((i0 + 2048) & 127) * 4) = t4;
        *(u64*)(slds + ((i0 + 2560) >> 7) * 520 + ((i0 + 2560) & 127) * 4) = t5;
        *(u64*)(slds + ((i0 + 3072) >> 7) * 520 + ((i0 + 3072) & 127) * 4) = t6;
        *(u64*)(slds + ((i0 + 3584) >> 7) * 520 + ((i0 + 3584) & 127) * 4) = t7;
      }
      __syncthreads();
      {
        f32x4 acc = {0.f, 0.f, 0.f, 0.f};
#pragma unroll
        for (int k0 = 0; k0 < 512; k0 += 32) {
          short8 a = *(const short8*)(slds + (mt * 16 + fr) * 520 + k0 + fq * 8);
          short8 bq = *(const short8*)(wrow + k0 + fq * 8);
          acc = __builtin_amdgcn_mfma_f32_16x16x32_bf16(a, bq, acc, 0, 0, 0);
        }
#pragma unroll
        for (int j = 0; j < 4; ++j)
          glds[(mt * 16 + fq * 4 + j) * 68 + nt * 16 + fr] = acc[j] + bv;
      }
      __syncthreads();
      {
        int b = tid >> 4, q = tid & 15;
        const float* gp = glds + b * 68 + q * 4;
        st_x64(gout64 + b * 1024 + g * 32 + q * 2, pack2f(gp[0], gp[1]));
        st_x64(gout64 + b * 1024 + g * 32 + q * 2 + 1, pack2f(gp[2], gp[3]));
      }
      asm volatile("s_waitcnt vmcnt(0)" ::: "memory");
      __syncthreads();
      if (tid == 0) st_flag(&gflag[t * 32 + g]);
    }
  } else {
    // ---- B role: one block per batch ----
    const int b = blk - 32;
    float* gout_f = (float*)smem;                            // 2048 f32
    unsigned short* sout = (unsigned short*)(smem + 8192);   // 512 bf16
    float* raw = (float*)(smem + 9216);                      // 64
    float* aaw = (float*)(smem + 9472);                      // 64
    float* vlds = (float*)(smem + 9728);                     // 512 f32
    vlds[tid] = attnV[tid];
    const int s_i = tid >> 3, l8 = tid & 7;
    float sreg = s0f[b * 512 + tid];
    __syncthreads();
    for (int t = 0; t < 47; ++t) {
      poll_flags(&gflag[t * 32], 32, tid);
      {
        u64 v0 = ld_x64(gout64 + b * 1024 + tid * 2);
        u64 v1 = ld_x64(gout64 + b * 1024 + tid * 2 + 1);
        ((u64*)gout_f)[tid * 2] = v0;
        ((u64*)gout_f)[tid * 2 + 1] = v1;
      }
      __syncthreads();
      // scores: energy[b,s] = v . tanh(sproj + encproj)
      {
        float part = 0.f;
        const float* gp = gout_f + l8 * 64;
        const unsigned short* ep = epf + ((size_t)b * 64 + s_i) * 512 + l8 * 64;
        const float* vv = vlds + l8 * 64;
#pragma unroll
        for (int jc = 0; jc < 8; ++jc) {
          short8 e8 = *(const short8*)(ep + jc * 8);
          float4 g0 = *(const float4*)(gp + jc * 8);
          float4 g1 = *(const float4*)(gp + jc * 8 + 4);
          float4 v0 = *(const float4*)(vv + jc * 8);
          float4 v1 = *(const float4*)(vv + jc * 8 + 4);
          part += tanh_fast(g0.x + bf2f((unsigned short)e8[0])) * v0.x;
          part += tanh_fast(g0.y + bf2f((unsigned short)e8[1])) * v0.y;
          part += tanh_fast(g0.z + bf2f((unsigned short)e8[2])) * v0.z;
          part += tanh_fast(g0.w + bf2f((unsigned short)e8[3])) * v0.w;
          part += tanh_fast(g1.x + bf2f((unsigned short)e8[4])) * v1.x;
          part += tanh_fast(g1.y + bf2f((unsigned short)e8[5])) * v1.y;
          part += tanh_fast(g1.z + bf2f((unsigned short)e8[6])) * v1.z;
          part += tanh_fast(g1.w + bf2f((unsigned short)e8[7])) * v1.w;
        }
        part += __shfl_xor(part, 1);
        part += __shfl_xor(part, 2);
        part += __shfl_xor(part, 4);
        if (l8 == 0) raw[s_i] = part;
      }
      __syncthreads();
      if (tid < 64) {
        float x = raw[tid];
        float m = x;
#pragma unroll
        for (int k = 1; k < 64; k <<= 1) m = fmaxf(m, __shfl_xor(m, k));
        float e = __expf(x - m);
        float s = e;
#pragma unroll
        for (int k = 1; k < 64; k <<= 1) s += __shfl_xor(s, k);
        aaw[tid] = e * __builtin_amdgcn_rcpf(s);
      }
      __syncthreads();
      float c0 = 0.f, c1 = 0.f, g0a = 0.f, g1a = 0.f, g2a = 0.f;
      {
        const unsigned short* eb = ebo + (size_t)b * 64 * 1024 + tid;
        const unsigned short* e2 = EP2b + (size_t)b * 64 * 1536 + tid;
#pragma unroll 8
        for (int s2 = 0; s2 < 64; ++s2) {
          float a = aaw[s2];
          c0 += a * bf2f(eb[(size_t)s2 * 1024]);
          c1 += a * bf2f(eb[(size_t)s2 * 1024 + 512]);
          g0a += a * bf2f(e2[(size_t)s2 * 1536]);
          g1a += a * bf2f(e2[(size_t)s2 * 1536 + 512]);
          g2a += a * bf2f(e2[(size_t)s2 * 1536 + 1024]);
        }
      }
      const float* gie = Gie + ((size_t)t * 32 + b) * 1536;
      float rr = sigm_fast(gie[tid] + g0a + gout_f[512 + tid]);
      float zz = sigm_fast(gie[512 + tid] + g1a + gout_f[1024 + tid]);
      float nn = tanh_fast(gie[1024 + tid] + g2a + rr * gout_f[1536 + tid]);
      float s2v = (1.f - zz) * nn + zz * sreg;
      sreg = s2v;
      sout[tid] = f2bf(s2v);
      __syncthreads();
      if (tid < 128)
        st_x64(smb + ((t + 1) & 1) * 4096 + b * 128 + tid, *(const u64*)(sout + tid * 4));
      asm volatile("s_waitcnt vmcnt(0)" ::: "memory");
      __syncthreads();
      if (tid == 0) st_flag(&sflag[t * 32 + b]);
      size_t zrow = ((size_t)t * 32 + b) * 2048;
      Zbf[zrow + tid] = f2bf(s2v);
      Zbf[zrow + 512 + tid] = f2bf(c0);
      Zbf[zrow + 1024 + tid] = f2bf(c1);
    }
  }
}

extern "C" void kernel_launch(void* const* d_in, const int* in_sizes, int n_in,
                              void* d_out, int out_size, void* d_ws, size_t ws_size,
                              hipStream_t stream) {
  (void)in_sizes; (void)n_in; (void)out_size;
  const int* src = (const int*)d_in[0];
  const int* trg = (const int*)d_in[1];
  const float* emb = (const float*)d_in[2];
  const float* encf_Wih = (const float*)d_in[3];
  const float* encf_Whh = (const float*)d_in[4];
  const float* encf_bih = (const float*)d_in[5];
  const float* encf_bhh = (const float*)d_in[6];
  const float* encb_Wih = (const float*)d_in[7];
  const float* encb_Whh = (const float*)d_in[8];
  const float* encb_bih = (const float*)d_in[9];
  const float* encb_bhh = (const float*)d_in[10];
  const float* fc_W = (const float*)d_in[11];
  const float* fc_b = (const float*)d_in[12];
  const float* attn_W = (const float*)d_in[13];
  const float* attn_v = (const float*)d_in[14];
  const float* dec_Wih = (const float*)d_in[15];
  const float* dec_Whh = (const float*)d_in[16];
  const float* dec_bih = (const float*)d_in[17];
  const float* dec_bhh = (const float*)d_in[18];
  const float* out_W = (const float*)d_in[19];
  const float* out_b = (const float*)d_in[20];
  float* out = (float*)d_out;

  char* p = (char*)d_ws;
  size_t off = 0;
  auto alloc = [&](size_t bytes) {
    void* r = p + off;
    off = (off + bytes + 255) & ~(size_t)255;
    return r;
  };
  // flags: gflag[47*32] | sflag[47*32] | hflag[2*64*16]
  const int NFLG = 47 * 32 * 2 + 2048;
  int* flg = (int*)alloc(NFLG * 4);
  int* gflag = flg;
  int* sflag = flg + 47 * 32;
  int* hflag = flg + 47 * 32 * 2;
  unsigned short* xbf = (unsigned short*)alloc((size_t)2048 * 512 * 2);
  unsigned short* ebf = (unsigned short*)alloc((size_t)1536 * 512 * 2);
  unsigned short* Zbf = (unsigned short*)alloc((size_t)1536 * 2048 * 2);
  float* Gif = (float*)alloc((size_t)2048 * 1536 * 4);
  float* Gib = (float*)alloc((size_t)2048 * 1536 * 4);
  float* Gie = (float*)alloc((size_t)1536 * 1536 * 4);
  unsigned short* ebo = (unsigned short*)alloc((size_t)2048 * 1024 * 2);
  unsigned short* epf = (unsigned short*)alloc((size_t)2048 * 512 * 2);
  unsigned short* EP2b = (unsigned short*)alloc((size_t)2048 * 1536 * 2);
  unsigned short* whFbf = (unsigned short*)alloc((size_t)1536 * 512 * 2);
  unsigned short* whBbf = (unsigned short*)alloc((size_t)1536 * 512 * 2);
  unsigned short* Wcat = (unsigned short*)alloc((size_t)2048 * 512 * 2);
  u64* hmb = (u64*)alloc((size_t)2 * 2 * 4096 * 8);
  float* hcat = (float*)alloc((size_t)32 * 1024 * 4);
  float* s0raw = (float*)alloc((size_t)32 * 512 * 4);
  float* s0f = (float*)alloc((size_t)32 * 512 * 4);
  u64* smb = (u64*)alloc((size_t)2 * 4096 * 8);
  u64* gout64 = (u64*)alloc((size_t)32 * 1024 * 8);
  unsigned short* outWbf = (unsigned short*)alloc((size_t)32000 * 2048 * 2);
  const bool bigB = (off <= ws_size);

  hipMemsetAsync(flg, 0, NFLG * 4, stream);
  hipMemsetAsync(hmb, 0, (size_t)2 * 2 * 4096 * 8, stream);
  hipMemsetAsync(d_out, 0, (size_t)32 * 32000 * 4, stream);

  prep_gather<<<3584, 128, 0, stream>>>(src, trg, emb, xbf, ebf, Zbf);
  cvt_weights<<<5120, 64, 0, stream>>>(encf_Whh, encb_Whh, attn_W, dec_Whh,
                                       whFbf, whBbf, Wcat);

  gemm_kernel<true, false, false><<<dim3(16, 12), 256, 0, stream>>>(
      xbf, 512, encf_Wih, 512, 0, encf_bih, Gif, 1536, 512, 2048, 0);
  gemm_kernel<true, false, false><<<dim3(16, 12), 256, 0, stream>>>(
      xbf, 512, encb_Wih, 512, 0, encb_bih, Gib, 1536, 512, 2048, 0);
  gemm_kernel<true, false, false><<<dim3(12, 12), 256, 0, stream>>>(
      ebf, 512, dec_Wih, 1536, 0, dec_bih, Gie, 1536, 512, 1536, 0);

  const int nCvtBlocks = bigB ? 200 : 0;
  enc_all<<<32 + nCvtBlocks, 512, 0, stream>>>(
      Gif, Gib, whFbf, whBbf, encf_bhh, encb_bhh, hmb, ebo, hcat,
      out_W, outWbf, bigB ? (long long)32000 * 2048 / 4 : 0, hflag);

  gemm_kernel<false, false, false><<<dim3(1, 4), 256, 0, stream>>>(
      hcat, 1024, fc_W, 1024, 0, fc_b, s0raw, 512, 1024, 32, 0);
  tanh_s0<<<32, 512, 0, stream>>>(s0raw, s0f, (unsigned short*)smb);

  gemm_kernel<true, false, true><<<dim3(16, 4), 256, 0, stream>>>(
      ebo, 1024, attn_W, 1536, 512, nullptr, epf, 512, 1024, 2048, 0);
  gemm_kernel<true, false, true><<<dim3(16, 12), 256, 0, stream>>>(
      ebo, 1024, dec_Wih, 1536, 512, nullptr, EP2b, 1536, 1024, 2048, 0);

  dec_all<<<64, 512, 0, stream>>>(Wcat, dec_bhh, attn_v, smb, s0f,
                                  epf, ebo, EP2b, Gie, gout64, Zbf, gflag, sflag);

  if (bigB) {
    hipFuncSetAttribute((const void*)gemm_big8,
                        hipFuncAttributeMaxDynamicSharedMemorySize, 131072);
    gemm_big8<<<750, 512, 131072, stream>>>(Zbf, outWbf, out_b, out);
  } else {
    gemm_kernel<true, false, false><<<dim3(12, 250), 256, 0, stream>>>(
        Zbf, 2048, out_W, 2048, 0, out_b, out, 32000, 2048, 1504, 32);
  }
}